// Round 5
// baseline (345.455 us; speedup 1.0000x reference)
//
#include <hip/hip_runtime.h>
#include <hip/hip_bf16.h>

// ---------- types ----------
typedef short short8 __attribute__((ext_vector_type(8)));
typedef float f32x4 __attribute__((ext_vector_type(4)));

#define N_TOKENS 2048
#define D_MODEL 1024
#define D_FF 4096
#define N_EXPERTS 8
#define TOTAL_SLOTS (N_TOKENS * 2)
#define BK 32
#define SPLITK2 4
#define KC2 (D_FF / SPLITK2)   // 1024 K per gemm2 block

static __device__ __forceinline__ unsigned int f2u(float f) {
    union { float f; unsigned int u; } v; v.f = f; return v.u;
}

// fp32 -> bf16 bits, round-to-nearest-even (scalar)
static __device__ __forceinline__ unsigned short f2bf(float f) {
    unsigned int u = f2u(f);
    unsigned int r = (u + 0x7fffu + ((u >> 16) & 1u)) >> 16;
    return (unsigned short)r;
}

// two fp32 -> packed bf16x2 (v_cvt_pk_bf16_f32)
static __device__ __forceinline__ unsigned int pk2bf(float a, float b) {
    __hip_bfloat162 t = __float22bfloat162_rn(float2{a, b});
    unsigned int u;
    __builtin_memcpy(&u, &t, 4);
    return u;
}

// async global->LDS, 16B per lane (lane l -> base + l*16; global addr per-lane)
typedef __attribute__((address_space(1))) const unsigned int GU;
typedef __attribute__((address_space(3))) unsigned int LU;
static __device__ __forceinline__ void gload_lds16(const void* g, void* l) {
    __builtin_amdgcn_global_load_lds((GU*)g, (LU*)l, 16, 0, 0);
}

// ---------- kernel: weights fp32 -> bf16 (streaming, grid-stride) ----------
__global__ __launch_bounds__(256) void cvt_w_kernel(const float* __restrict__ src,
                                                    unsigned short* __restrict__ dst,
                                                    int n8) {
    int i = blockIdx.x * 256 + threadIdx.x;
    const int stride = gridDim.x * 256;
    for (; i < n8; i += stride) {
        const size_t b = (size_t)i * 8;
        float4 f0 = *(const float4*)(src + b);
        float4 f1 = *(const float4*)(src + b + 4);
        uint4 o;
        o.x = pk2bf(f0.x, f0.y); o.y = pk2bf(f0.z, f0.w);
        o.z = pk2bf(f1.x, f1.y); o.w = pk2bf(f1.z, f1.w);
        *(uint4*)(dst + b) = o;
    }
}

// ---------- kernel: x fp32 -> bf16 ----------
__global__ __launch_bounds__(256) void cvt_x_kernel(const float* __restrict__ x,
                                                    unsigned short* __restrict__ xb) {
    int i = (blockIdx.x * 256 + threadIdx.x) * 4;
    if (i >= N_TOKENS * D_MODEL) return;
    float4 f = *(const float4*)(x + i);
    uint2 o;
    o.x = pk2bf(f.x, f.y);
    o.y = pk2bf(f.z, f.w);
    *(uint2*)(xb + i) = o;
}

// ---------- kernel: gating (exact fp32) ----------
__global__ __launch_bounds__(64) void gate_kernel(const float* __restrict__ x,
                                                  const float* __restrict__ gw,
                                                  int* __restrict__ counts,
                                                  int* __restrict__ tok_e,
                                                  float* __restrict__ tok_w) {
    const int n = blockIdx.x;
    const int lane = threadIdx.x;
    float p[N_EXPERTS];
#pragma unroll
    for (int e = 0; e < N_EXPERTS; ++e) p[e] = 0.f;
    const float* xr = x + n * D_MODEL;
    for (int d = lane; d < D_MODEL; d += 64) {
        float xv = xr[d];
#pragma unroll
        for (int e = 0; e < N_EXPERTS; ++e) p[e] += xv * gw[e * D_MODEL + d];
    }
#pragma unroll
    for (int e = 0; e < N_EXPERTS; ++e) {
        float v = p[e];
        for (int o = 32; o > 0; o >>= 1) v += __shfl_down(v, o);
        p[e] = v;
    }
    if (lane == 0) {
        int b1 = 0; float v1 = p[0];
        for (int e = 1; e < N_EXPERTS; ++e) if (p[e] > v1) { v1 = p[e]; b1 = e; }
        int b2 = -1; float v2 = -1e30f;
        for (int e = 0; e < N_EXPERTS; ++e) if (e != b1 && p[e] > v2) { v2 = p[e]; b2 = e; }
        float e2 = __expf(v2 - v1);
        float s = 1.f + e2;
        tok_e[n * 2 + 0] = b1; tok_w[n * 2 + 0] = 1.f / s;
        tok_e[n * 2 + 1] = b2; tok_w[n * 2 + 1] = e2 / s;
        atomicAdd(&counts[b1], 1);
        atomicAdd(&counts[b2], 1);
    }
}

// ---------- kernel: exclusive scan of 8 counts ----------
__global__ void scan_kernel(const int* __restrict__ counts,
                            int* __restrict__ offsets, int* __restrict__ fill) {
    if (threadIdx.x == 0 && blockIdx.x == 0) {
        int s = 0;
        for (int e = 0; e < N_EXPERTS; ++e) { offsets[e] = s; fill[e] = s; s += counts[e]; }
    }
}

// ---------- kernel: route tokens into contiguous per-expert slots ----------
__global__ __launch_bounds__(256) void route_kernel(const int* __restrict__ tok_e,
                                                    const float* __restrict__ tok_w,
                                                    int* __restrict__ fill,
                                                    int* __restrict__ rows_tok,
                                                    float* __restrict__ rows_w) {
    int i = blockIdx.x * 256 + threadIdx.x;
    if (i >= TOTAL_SLOTS) return;
    int e = tok_e[i];
    float w = tok_w[i];
    int pos = atomicAdd(&fill[e], 1);
    rows_tok[pos] = i >> 1;
    rows_w[pos] = w;
}

// ---------- GEMM1: h = gelu(x_gathered @ w1[e]^T), bf16 out ----------
// 128x128 tile, BK=32, 4 waves, double-buffered LDS, plain __syncthreads (m97 structure).
// PRE=true: B staged from pre-converted bf16 weights via global_load_lds.
// PRE=false: B reg-loaded fp32 + cvt + ds_write (fallback if ws too small).
// grid: (D_FF/128, 16, 8), block 256
template <bool PRE>
__global__ __launch_bounds__(256, 4) void gemm1_kernel(
    const unsigned short* __restrict__ xb,
    const unsigned short* __restrict__ w1b,
    const float* __restrict__ w1f,
    const int* __restrict__ counts, const int* __restrict__ offsets,
    const int* __restrict__ rows_tok,
    unsigned short* __restrict__ h) {
    const int e = blockIdx.z;
    const int cnt = counts[e];
    const int mt = blockIdx.y;
    if (mt * 128 >= cnt) return;
    const int off = offsets[e];
    const int nt = blockIdx.x;

    __shared__ unsigned short As[2][128 * 32];
    __shared__ unsigned short Bs[2][128 * 32];

    const int tid = threadIdx.x, lane = tid & 63, wave = tid >> 6;
    const int wm = wave >> 1, wn = wave & 1;

    // A gather staging via glds: wave stages rows [wave*32, +32), lane l -> row l>>2, chunk l&3
    const int ac8 = lane & 3;
    int r0 = off + mt * 128 + wave * 32 + (lane >> 2);
    int r1 = r0 + 16;
    r0 = min(r0, TOTAL_SLOTS - 1);
    r1 = min(r1, TOTAL_SLOTS - 1);
    const unsigned short* ag0 = xb + (size_t)rows_tok[r0] * D_MODEL + ac8 * 8;
    const unsigned short* ag1 = xb + (size_t)rows_tok[r1] * D_MODEL + ac8 * 8;

    // B staging (PRE): same geometry on bf16 weights
    const int bgrow = nt * 128 + wave * 32 + (lane >> 2);
    const unsigned short* bg0 = w1b + (size_t)e * (D_FF * D_MODEL) + (size_t)bgrow * D_MODEL + ac8 * 8;
    // B staging (fallback fp32): row tid>>1, 16 floats at col (tid&1)*16
    const int brow = tid >> 1, bcol = (tid & 1) * 16;
    const float* bgf = w1f + (size_t)e * (D_FF * D_MODEL) + (size_t)(nt * 128 + brow) * D_MODEL + bcol;

    f32x4 acc[4][4];
#pragma unroll
    for (int i = 0; i < 4; ++i)
#pragma unroll
        for (int j = 0; j < 4; ++j) acc[i][j] = (f32x4){0.f, 0.f, 0.f, 0.f};

    auto stageA = [&](int buf, int t) {
        const int k = t * BK;
        gload_lds16(ag0 + k, &As[buf][(wave * 32) * 32]);
        gload_lds16(ag1 + k, &As[buf][(wave * 32 + 16) * 32]);
    };
    auto stageBpre = [&](int buf, int t) {
        const int k = t * BK;
        gload_lds16(bg0 + k, &Bs[buf][(wave * 32) * 32]);
        gload_lds16(bg0 + 16 * D_MODEL + k, &Bs[buf][(wave * 32 + 16) * 32]);
    };
    auto writeBf32 = [&](int buf, const float4& f0, const float4& f1,
                         const float4& f2, const float4& f3) {
        unsigned int bp[8];
        bp[0] = pk2bf(f0.x, f0.y); bp[1] = pk2bf(f0.z, f0.w);
        bp[2] = pk2bf(f1.x, f1.y); bp[3] = pk2bf(f1.z, f1.w);
        bp[4] = pk2bf(f2.x, f2.y); bp[5] = pk2bf(f2.z, f2.w);
        bp[6] = pk2bf(f3.x, f3.y); bp[7] = pk2bf(f3.z, f3.w);
        *(uint4*)&Bs[buf][brow * 32 + bcol]     = *(uint4*)&bp[0];
        *(uint4*)&Bs[buf][brow * 32 + bcol + 8] = *(uint4*)&bp[4];
    };

    // prologue: tile 0 -> buf 0
    stageA(0, 0);
    if constexpr (PRE) {
        stageBpre(0, 0);
    } else {
        float4 f0 = *(const float4*)(bgf + 0);
        float4 f1 = *(const float4*)(bgf + 4);
        float4 f2 = *(const float4*)(bgf + 8);
        float4 f3 = *(const float4*)(bgf + 12);
        writeBf32(0, f0, f1, f2, f3);
    }
    __syncthreads();

    const int KSTEPS = D_MODEL / BK;  // 32
#pragma unroll 2
    for (int t = 0; t < KSTEPS; ++t) {
        const int cur = t & 1, nxt = cur ^ 1;
        const bool more = (t + 1 < KSTEPS);
        float4 f0, f1, f2, f3;
        if (more) {
            stageA(nxt, t + 1);
            if constexpr (PRE) {
                stageBpre(nxt, t + 1);
            } else {
                const int k = (t + 1) * BK;
                f0 = *(const float4*)(bgf + k + 0);
                f1 = *(const float4*)(bgf + k + 4);
                f2 = *(const float4*)(bgf + k + 8);
                f3 = *(const float4*)(bgf + k + 12);
            }
        }
        short8 af[4], bfr[4];
#pragma unroll
        for (int mi = 0; mi < 4; ++mi)
            af[mi] = *(const short8*)&As[cur][(wm * 64 + mi * 16 + (lane & 15)) * 32 + (lane >> 4) * 8];
#pragma unroll
        for (int nj = 0; nj < 4; ++nj)
            bfr[nj] = *(const short8*)&Bs[cur][(wn * 64 + nj * 16 + (lane & 15)) * 32 + (lane >> 4) * 8];
#pragma unroll
        for (int mi = 0; mi < 4; ++mi)
#pragma unroll
            for (int nj = 0; nj < 4; ++nj)
                acc[mi][nj] = __builtin_amdgcn_mfma_f32_16x16x32_bf16(af[mi], bfr[nj], acc[mi][nj], 0, 0, 0);
        if constexpr (!PRE) {
            if (more) writeBf32(nxt, f0, f1, f2, f3);
        }
        __syncthreads();
    }

    // epilogue: exact-erf GELU, store bf16
    const int lr = (lane >> 4) * 4, lc = lane & 15;
#pragma unroll
    for (int mi = 0; mi < 4; ++mi) {
        const int mbase = mt * 128 + wm * 64 + mi * 16 + lr;
#pragma unroll
        for (int j = 0; j < 4; ++j) {
            const int m = mbase + j;
            if (m < cnt) {
#pragma unroll
                for (int nj = 0; nj < 4; ++nj) {
                    const int n = nt * 128 + wn * 64 + nj * 16 + lc;
                    float v = acc[mi][nj][j];
                    v = 0.5f * v * (1.0f + erff(v * 0.70710678118654752f));
                    h[(size_t)(off + m) * D_FF + n] = f2bf(v);
                }
            }
        }
    }
}

// ---------- GEMM2: out[tok] += w_slot * (h @ w2[e]^T), split-K x4 ----------
// grid: (D_MODEL/128, 16, 8*SPLITK2), block 256
template <bool PRE>
__global__ __launch_bounds__(256, 4) void gemm2_kernel(
    const unsigned short* __restrict__ h,
    const unsigned short* __restrict__ w2b,
    const float* __restrict__ w2f,
    const int* __restrict__ counts, const int* __restrict__ offsets,
    const int* __restrict__ rows_tok, const float* __restrict__ rows_w,
    float* __restrict__ out) {
    const int e = blockIdx.z >> 2;
    const int kc = blockIdx.z & 3;
    const int cnt = counts[e];
    const int mt = blockIdx.y;
    if (mt * 128 >= cnt) return;
    const int off = offsets[e];
    const int nt = blockIdx.x;

    __shared__ unsigned short As[2][128 * 32];
    __shared__ unsigned short Bs[2][128 * 32];

    const int tid = threadIdx.x, lane = tid & 63, wave = tid >> 6;
    const int wm = wave >> 1, wn = wave & 1;

    const int ac8 = lane & 3;
    int r0 = off + mt * 128 + wave * 32 + (lane >> 2);
    int r1 = r0 + 16;
    r0 = min(r0, TOTAL_SLOTS - 1);
    r1 = min(r1, TOTAL_SLOTS - 1);
    const unsigned short* ag0 = h + (size_t)r0 * D_FF + kc * KC2 + ac8 * 8;
    const unsigned short* ag1 = h + (size_t)r1 * D_FF + kc * KC2 + ac8 * 8;

    const int bgrow = nt * 128 + wave * 32 + (lane >> 2);
    const unsigned short* bg0 = w2b + (size_t)e * (D_MODEL * D_FF) + (size_t)bgrow * D_FF + kc * KC2 + ac8 * 8;
    const int brow = tid >> 1, bcol = (tid & 1) * 16;
    const float* bgf = w2f + (size_t)e * (D_MODEL * D_FF) + (size_t)(nt * 128 + brow) * D_FF + kc * KC2 + bcol;

    f32x4 acc[4][4];
#pragma unroll
    for (int i = 0; i < 4; ++i)
#pragma unroll
        for (int j = 0; j < 4; ++j) acc[i][j] = (f32x4){0.f, 0.f, 0.f, 0.f};

    auto stageA = [&](int buf, int t) {
        const int k = t * BK;
        gload_lds16(ag0 + k, &As[buf][(wave * 32) * 32]);
        gload_lds16(ag1 + k, &As[buf][(wave * 32 + 16) * 32]);
    };
    auto stageBpre = [&](int buf, int t) {
        const int k = t * BK;
        gload_lds16(bg0 + k, &Bs[buf][(wave * 32) * 32]);
        gload_lds16(bg0 + 16 * D_FF + k, &Bs[buf][(wave * 32 + 16) * 32]);
    };
    auto writeBf32 = [&](int buf, const float4& f0, const float4& f1,
                         const float4& f2, const float4& f3) {
        unsigned int bp[8];
        bp[0] = pk2bf(f0.x, f0.y); bp[1] = pk2bf(f0.z, f0.w);
        bp[2] = pk2bf(f1.x, f1.y); bp[3] = pk2bf(f1.z, f1.w);
        bp[4] = pk2bf(f2.x, f2.y); bp[5] = pk2bf(f2.z, f2.w);
        bp[6] = pk2bf(f3.x, f3.y); bp[7] = pk2bf(f3.z, f3.w);
        *(uint4*)&Bs[buf][brow * 32 + bcol]     = *(uint4*)&bp[0];
        *(uint4*)&Bs[buf][brow * 32 + bcol + 8] = *(uint4*)&bp[4];
    };

    stageA(0, 0);
    if constexpr (PRE) {
        stageBpre(0, 0);
    } else {
        float4 f0 = *(const float4*)(bgf + 0);
        float4 f1 = *(const float4*)(bgf + 4);
        float4 f2 = *(const float4*)(bgf + 8);
        float4 f3 = *(const float4*)(bgf + 12);
        writeBf32(0, f0, f1, f2, f3);
    }
    __syncthreads();

    const int KSTEPS = KC2 / BK;  // 32
#pragma unroll 2
    for (int t = 0; t < KSTEPS; ++t) {
        const int cur = t & 1, nxt = cur ^ 1;
        const bool more = (t + 1 < KSTEPS);
        float4 f0, f1, f2, f3;
        if (more) {
            stageA(nxt, t + 1);
            if constexpr (PRE) {
                stageBpre(nxt, t + 1);
            } else {
                const int k = (t + 1) * BK;
                f0 = *(const float4*)(bgf + k + 0);
                f1 = *(const float4*)(bgf + k + 4);
                f2 = *(const float4*)(bgf + k + 8);
                f3 = *(const float4*)(bgf + k + 12);
            }
        }
        short8 af[4], bfr[4];
#pragma unroll
        for (int mi = 0; mi < 4; ++mi)
            af[mi] = *(const short8*)&As[cur][(wm * 64 + mi * 16 + (lane & 15)) * 32 + (lane >> 4) * 8];
#pragma unroll
        for (int nj = 0; nj < 4; ++nj)
            bfr[nj] = *(const short8*)&Bs[cur][(wn * 64 + nj * 16 + (lane & 15)) * 32 + (lane >> 4) * 8];
#pragma unroll
        for (int mi = 0; mi < 4; ++mi)
#pragma unroll
            for (int nj = 0; nj < 4; ++nj)
                acc[mi][nj] = __builtin_amdgcn_mfma_f32_16x16x32_bf16(af[mi], bfr[nj], acc[mi][nj], 0, 0, 0);
        if constexpr (!PRE) {
            if (more) writeBf32(nxt, f0, f1, f2, f3);
        }
        __syncthreads();
    }

    const int lr = (lane >> 4) * 4, lc = lane & 15;
#pragma unroll
    for (int mi = 0; mi < 4; ++mi) {
        const int mbase = mt * 128 + wm * 64 + mi * 16 + lr;
#pragma unroll
        for (int j = 0; j < 4; ++j) {
            const int m = mbase + j;
            if (m < cnt) {
                const int tok = rows_tok[off + m];
                const float w = rows_w[off + m];
#pragma unroll
                for (int nj = 0; nj < 4; ++nj) {
                    const int n = nt * 128 + wn * 64 + nj * 16 + lc;
                    atomicAdd(&out[(size_t)tok * D_MODEL + n], w * acc[mi][nj][j]);
                }
            }
        }
    }
}

// ---------- workspace layout ----------
//   0            counts[8]
//   256          fill[8]
//   512          offsets[8]
//   768          tok_e   [4096] int
//   17152        tok_w   [4096] float
//   33536        rows_tok[4096] int
//   49920        rows_w  [4096] float
//   66560        xb  bf16 [2048][1024]      (4,194,304 B)
//   4,260,864    h   bf16 [4096][4096]      (33,554,432 B)
//   37,815,296   w1b bf16 [8][4096][1024]   (67,108,864 B)   [PRE only]
//   104,924,160  w2b bf16 [8][1024][4096]   (67,108,864 B)   [PRE only]
//   total PRE: 172,033,024 B

extern "C" void kernel_launch(void* const* d_in, const int* in_sizes, int n_in,
                              void* d_out, int out_size, void* d_ws, size_t ws_size,
                              hipStream_t stream) {
    const float* x  = (const float*)d_in[0];
    const float* gw = (const float*)d_in[1];
    const float* w1 = (const float*)d_in[2];
    const float* w2 = (const float*)d_in[3];
    float* out = (float*)d_out;

    char* ws = (char*)d_ws;
    int*   counts   = (int*)(ws + 0);
    int*   fill     = (int*)(ws + 256);
    int*   offsets  = (int*)(ws + 512);
    int*   tok_e    = (int*)(ws + 768);
    float* tok_w    = (float*)(ws + 17152);
    int*   rows_tok = (int*)(ws + 33536);
    float* rows_w   = (float*)(ws + 49920);
    unsigned short* xb  = (unsigned short*)(ws + 66560);
    unsigned short* h   = (unsigned short*)(ws + 4260864);
    unsigned short* w1b = (unsigned short*)(ws + 37815296ull);
    unsigned short* w2b = (unsigned short*)(ws + 104924160ull);
    const bool pre = (ws_size >= 172033024ull);

    hipMemsetAsync(counts, 0, 32, stream);
    hipMemsetAsync(d_out, 0, (size_t)out_size * sizeof(float), stream);

    if (pre) {
        const int n8 = (N_EXPERTS * D_FF * D_MODEL) / 8;  // 4,194,304
        cvt_w_kernel<<<dim3(2048), dim3(256), 0, stream>>>(w1, w1b, n8);
        cvt_w_kernel<<<dim3(2048), dim3(256), 0, stream>>>(w2, w2b, n8);
    }
    cvt_x_kernel<<<dim3((N_TOKENS * D_MODEL / 4 + 255) / 256), dim3(256), 0, stream>>>(x, xb);
    gate_kernel<<<dim3(N_TOKENS), dim3(64), 0, stream>>>(x, gw, counts, tok_e, tok_w);
    scan_kernel<<<dim3(1), dim3(64), 0, stream>>>(counts, offsets, fill);
    route_kernel<<<dim3((TOTAL_SLOTS + 255) / 256), dim3(256), 0, stream>>>(tok_e, tok_w, fill, rows_tok, rows_w);

    if (pre) {
        gemm1_kernel<true><<<dim3(D_FF / 128, 16, N_EXPERTS), dim3(256), 0, stream>>>(
            xb, w1b, w1, counts, offsets, rows_tok, h);
        gemm2_kernel<true><<<dim3(D_MODEL / 128, 16, N_EXPERTS * SPLITK2), dim3(256), 0, stream>>>(
            h, w2b, w2, counts, offsets, rows_tok, rows_w, out);
    } else {
        gemm1_kernel<false><<<dim3(D_FF / 128, 16, N_EXPERTS), dim3(256), 0, stream>>>(
            xb, w1b, w1, counts, offsets, rows_tok, h);
        gemm2_kernel<false><<<dim3(D_MODEL / 128, 16, N_EXPERTS * SPLITK2), dim3(256), 0, stream>>>(
            h, w2b, w2, counts, offsets, rows_tok, rows_w, out);
    }
}